// Round 12
// baseline (4786.462 us; speedup 1.0000x reference)
//
#include <hip/hip_runtime.h>
#include <cstdint>
#include <cmath>

typedef unsigned short u16;
typedef unsigned long long u64;
typedef __attribute__((ext_vector_type(8))) short short8;
typedef __attribute__((ext_vector_type(4))) float f32x4;

#define SEQ 1024
#define HD 1024
#define GD 4096
#define NB 8
#define MROWS 8192   // NB*SEQ

__device__ __forceinline__ u16 f2bf(float f) {
  union { float f; uint32_t u; } c; c.f = f;
  uint32_t u = c.u;
  uint32_t r = (u + 0x7fffu + ((u >> 16) & 1u)) >> 16;
  return (u16)r;
}
__device__ __forceinline__ float bf2f(u16 h) {
  union { uint32_t u; float f; } c; c.u = ((uint32_t)h) << 16;
  return c.f;
}

// ---------------- fp32 -> bf16 convert ----------------
__global__ void k_tobf16(const float* __restrict__ in, u16* __restrict__ out, long n) {
  long i = ((long)blockIdx.x * 256L + threadIdx.x) * 4;
  long st = (long)gridDim.x * 1024L;
  for (; i < n; i += st) {
    float4 v = *(const float4*)(in + i);
    ushort4 o;
    o.x = f2bf(v.x); o.y = f2bf(v.y); o.z = f2bf(v.z); o.w = f2bf(v.w);
    *(ushort4*)(out + i) = o;
  }
}

// ---------------- bf16 MFMA GEMM: C[m][n] = sum_k A[m][k]*Bw[n][k] (+epilogue) ----
// MODE 0: outb[(t*8+b)*4096 + col] = bf16(acc + bias[n])   (t-major for scan)
// MODE 1: outf = gelu(acc + bias[n]) + res[m][n]           (exact gelu)
template<int MODE>
__global__ __launch_bounds__(256, 1) void k_gemm(
    const u16* __restrict__ A, const u16* __restrict__ Bw,
    const float* __restrict__ bias, const float* __restrict__ res,
    u16* __restrict__ outb, float* __restrict__ outf, int N, int K)
{
  __shared__ u16 As[128][40];
  __shared__ u16 Bs[128][40];
  const int tid = threadIdx.x;
  const int wid = tid >> 6, lane = tid & 63;
  const int wm = wid >> 1, wn = wid & 1;
  const int r = lane & 15, q = lane >> 4;
  const long m0 = (long)blockIdx.y * 128, n0 = (long)blockIdx.x * 128;
  const int srow = tid >> 1, sseg = (tid & 1) * 16;

  f32x4 acc[4][4];
#pragma unroll
  for (int i = 0; i < 4; ++i)
#pragma unroll
    for (int j = 0; j < 4; ++j) acc[i][j] = (f32x4){0.f, 0.f, 0.f, 0.f};

  const u16* ag = A + (m0 + srow) * (long)K + sseg;
  const u16* bg = Bw + (n0 + srow) * (long)K + sseg;

  for (int k0 = 0; k0 < K; k0 += 32) {
    short8 av0 = *(const short8*)(ag + k0);
    short8 av1 = *(const short8*)(ag + k0 + 8);
    short8 bv0 = *(const short8*)(bg + k0);
    short8 bv1 = *(const short8*)(bg + k0 + 8);
    __syncthreads();
    *(short8*)&As[srow][sseg]     = av0;
    *(short8*)&As[srow][sseg + 8] = av1;
    *(short8*)&Bs[srow][sseg]     = bv0;
    *(short8*)&Bs[srow][sseg + 8] = bv1;
    __syncthreads();
    short8 bfr[4];
#pragma unroll
    for (int ni = 0; ni < 4; ++ni)
      bfr[ni] = *(const short8*)&Bs[wn * 64 + ni * 16 + r][q * 8];
#pragma unroll
    for (int mi = 0; mi < 4; ++mi) {
      short8 afr = *(const short8*)&As[wm * 64 + mi * 16 + r][q * 8];
#pragma unroll
      for (int ni = 0; ni < 4; ++ni)
        acc[mi][ni] = __builtin_amdgcn_mfma_f32_16x16x32_bf16(afr, bfr[ni], acc[mi][ni], 0, 0, 0);
    }
  }

#pragma unroll
  for (int mi = 0; mi < 4; ++mi)
#pragma unroll
    for (int ni = 0; ni < 4; ++ni) {
      long col = n0 + wn * 64 + ni * 16 + r;
      float bc = bias[col];
#pragma unroll
      for (int rr = 0; rr < 4; ++rr) {
        long row = m0 + wm * 64 + mi * 16 + q * 4 + rr;
        float v = acc[mi][ni][rr] + bc;
        if (MODE == 0) {
          long b = row >> 10, t = row & 1023;
          outb[((t * 8 + b) << 12) + col] = f2bf(v);
        } else {
          float ge = 0.5f * v * (1.0f + erff(v * 0.70710678118654752f));
          outf[row * N + col] = ge + res[row * N + col];
        }
      }
    }
}

// ---------------- persistent sLSTM scan (R11 + MALL-spread exchange) --------
// 256 WGs x 512 threads (8 waves). b = wgid&7, c = wgid>>3 (units [c*32,c*32+32)
// of batch b). Exchange protocol identical to R11 (self-validating tagged
// words, agent relaxed, no flags/acks) but each writer WG's 128B chunk now
// lives in its OWN 4KB page -> the poll hot-set spreads across MALL channels
// instead of hammering 4KB/batch. Page(b,par,c) = ((b*2+par)*32 + c).
// Publish = 32 direct tagged-u32 stores (no pack shfls). setprio(1) around
// the gate+publish region (critical wave).
__global__ __launch_bounds__(512, 1) void k_scan(
    const u16* __restrict__ xp, const u16* __restrict__ Rb,
    u16* __restrict__ hseq, u64* __restrict__ hx, int tagbase)
{
  __shared__ float Dred[2][8][128];   // [par][wave][g*32+u]
  __shared__ u16 xpf[4][4][32];       // [t&3][g][u]
  __shared__ u16 hhist[2][32][32];    // [bank][t&31][u]

  const int tid = threadIdx.x;
  const int wgid = blockIdx.x;
  const int b = wgid & 7, c = wgid >> 3;
  const int w = tid >> 6, lane = tid & 63;
  const int r = lane & 15, q = lane >> 4;

  // ---- weights: wave w holds k in [w*128,(w+1)*128) for 128 local rows.
  // local row j*16+r -> gate g = (j*16+r)>>5, unit u = (j*16+r)&31.
  short8 wt[8][4];
#pragma unroll
  for (int j = 0; j < 8; ++j) {
    const int coll = j * 16 + r;
    const int g = coll >> 5, u = coll & 31;
    const u16* src = Rb + ((long)(g * HD + c * 32 + u)) * HD + w * 128 + q * 8;
#pragma unroll
    for (int s = 0; s < 4; ++s)
      wt[j][s] = *(const short8*)(src + s * 32);
  }

  // prologue: xpf[0],xpf[1]  (xp t-major: ((t*8+b)<<12) + g*1024 + c*32 + u)
  if (w == 0 && lane < 32) {
    const int g = lane >> 3, o4 = (lane & 7) * 4;
#pragma unroll
    for (int t = 0; t < 2; ++t) {
      u64 v = *(const u64*)(xp + ((long)(t * 8 + b) << 12) + g * 1024 + c * 32 + o4);
      *(u64*)&xpf[t][g][o4] = v;
    }
  }
  __syncthreads();

  float c_s = 0.f, n_s = 0.f, m_s = 0.f;

  // reader mapping: global u64 index g64 = w*64+lane covers h[2*g64, 2*g64+2);
  // writer chunk = g64>>4, word-in-page = g64&15.
  const int rd_chunk = (w * 64 + lane) >> 4;
  const int rd_word  = (w * 64 + lane) & 15;

  for (int i = 0; i < SEQ; ++i) {
    // ---- phase A (all 8 waves): Dred[i&1] = h_{i-1} @ R^T partials
    if (i > 0) {
      const unsigned tg = (unsigned)(tagbase + i - 1) & 0xffffu;
      const u64* src = hx + ((long)((b * 2 + ((i - 1) & 1)) * 32 + rd_chunk) << 9)
                       + rd_word;
      u64 hv;
#pragma unroll 1
      for (;;) {
        hv = __hip_atomic_load(src, __ATOMIC_RELAXED, __HIP_MEMORY_SCOPE_AGENT);
        if ((((unsigned)(hv >> 16)) & 0xffffu) == tg &&
            ((unsigned)(hv >> 48)) == tg) break;
      }
      unsigned pk = ((unsigned)hv & 0xffffu) | (((unsigned)(hv >> 32) & 0xffffu) << 16);

      f32x4 acc[8];
#pragma unroll
      for (int j = 0; j < 8; ++j) acc[j] = (f32x4){0.f, 0.f, 0.f, 0.f};
#pragma unroll
      for (int s = 0; s < 4; ++s) {
        union { unsigned x[4]; short8 v; } af;
#pragma unroll
        for (int m2 = 0; m2 < 4; ++m2)
          af.x[m2] = __shfl(pk, s * 16 + q * 4 + m2, 64);
#pragma unroll
        for (int j = 0; j < 8; ++j)
          acc[j] = __builtin_amdgcn_mfma_f32_16x16x32_bf16(af.v, wt[j][s], acc[j], 0, 0, 0);
      }
      if (q == 0) {
#pragma unroll
        for (int j = 0; j < 8; ++j)
          Dred[i & 1][w][j * 16 + r] = acc[j][0];      // D row 0 = h slice result
      }
    }
    __syncthreads();

    // ---- phase C: wave 7 = gates + tagged publish; wave 0 = xp prefetch;
    //               wave 6 = amortized hseq dump
    if (w == 7) {
      __builtin_amdgcn_s_setprio(1);
      const int u = lane & 31;
      float pre[4];
#pragma unroll
      for (int g = 0; g < 4; ++g) {
        float s2 = bf2f(xpf[i & 3][g][u]);
        if (i > 0) {
#pragma unroll
          for (int w2 = 0; w2 < 8; ++w2) s2 += Dred[i & 1][w2][g * 32 + u];
        }
        pre[g] = s2;
      }
      float og = 1.f / (1.f + __expf(-pre[3]));        // early: hides exp latency
      float mn = fmaxf(pre[1] + m_s, pre[0]);
      float ig = __expf(pre[0] - mn);
      float fg = __expf(pre[1] + m_s - mn);
      float e2 = __expf(2.f * pre[2]);
      float th = 1.f - 2.f / (e2 + 1.f);               // tanh(pre[2])
      c_s = fg * c_s + ig * th;
      n_s = fg * n_s + ig;
      m_s = mn;
      float h = og * (c_s / n_s);

      unsigned hu = (unsigned)f2bf(h);
      // publish FIRST (critical path): 32 direct tagged-u32 stores into own page
      if (lane < 32 && i < SEQ - 1) {
        unsigned word = (((unsigned)(tagbase + i) & 0xffffu) << 16) | hu;
        uint32_t* dst = (uint32_t*)hx
                        + ((long)((b * 2 + (i & 1)) * 32 + c) << 10) + lane;
        __hip_atomic_store(dst, word, __ATOMIC_RELAXED, __HIP_MEMORY_SCOPE_AGENT);
      }
      __builtin_amdgcn_s_setprio(0);
      // history for amortized hseq dump (off critical path)
      if (lane < 32) hhist[(i >> 5) & 1][i & 31][lane] = (u16)hu;
    } else if (w == 0 && lane < 32 && i + 2 < SEQ) {
      const int g = lane >> 3, o4 = (lane & 7) * 4;
      u64 v = *(const u64*)(xp + ((long)((i + 2) * 8 + b) << 12) + g * 1024 + c * 32 + o4);
      *(u64*)&xpf[(i + 2) & 3][g][o4] = v;
    } else if (w == 6 && lane < 32 && i > 0 && (i & 31) == 0) {
      // dump previous 32-step bank to hseq (plain stores; visible at kernel end)
      const int bank = ((i >> 5) & 1) ^ 1;
#pragma unroll
      for (int j = 0; j < 4; ++j) {
        short8 v = *(const short8*)&hhist[bank][lane][j * 8];
        *(short8*)(hseq + ((long)(b * SEQ + (i - 32 + lane))) * HD + c * 32 + j * 8) = v;
      }
    }
    // single barrier/step: next iteration's phase A starts with its own poll
  }

  // order wave 7's final hhist writes before the epilogue dump (R10 lesson)
  __syncthreads();

  // epilogue: dump last 32 steps (bank 1 holds steps 992..1023)
  if (w == 6 && lane < 32) {
#pragma unroll
    for (int j = 0; j < 4; ++j) {
      short8 v = *(const short8*)&hhist[1][lane][j * 8];
      *(short8*)(hseq + ((long)(b * SEQ + (SEQ - 32 + lane))) * HD + c * 32 + j * 8) = v;
    }
  }
}

// ---------------- row LayerNorm (D=1024), fp32 out + bf16 copy ----------------
__global__ __launch_bounds__(256, 1) void k_ln(
    const float* __restrict__ z, const float* __restrict__ gamma, const float* __restrict__ beta,
    float* __restrict__ xout, u16* __restrict__ xb)
{
  const int row = blockIdx.x, tid = threadIdx.x;
  const float4 v = *(const float4*)(z + (long)row * HD + tid * 4);
  float s = v.x + v.y + v.z + v.w;
  float s2 = v.x * v.x + v.y * v.y + v.z * v.z + v.w * v.w;
#pragma unroll
  for (int off = 32; off > 0; off >>= 1) {
    s += __shfl_down(s, off, 64);
    s2 += __shfl_down(s2, off, 64);
  }
  __shared__ float red[8];
  const int wid = tid >> 6, lane = tid & 63;
  if (lane == 0) { red[wid] = s; red[4 + wid] = s2; }
  __syncthreads();
  float su = red[0] + red[1] + red[2] + red[3];
  float sq = red[4] + red[5] + red[6] + red[7];
  float mu = su * (1.f / 1024.f);
  float var = sq * (1.f / 1024.f) - mu * mu;
  float rs = rsqrtf(var + 1e-5f);
  const float4 g  = *(const float4*)(gamma + tid * 4);
  const float4 bt = *(const float4*)(beta + tid * 4);
  float4 o;
  o.x = (v.x - mu) * rs * g.x + bt.x;
  o.y = (v.y - mu) * rs * g.y + bt.y;
  o.z = (v.z - mu) * rs * g.z + bt.z;
  o.w = (v.w - mu) * rs * g.w + bt.w;
  *(float4*)(xout + (long)row * HD + tid * 4) = o;
  ushort4 ob;
  ob.x = f2bf(o.x); ob.y = f2bf(o.y); ob.z = f2bf(o.z); ob.w = f2bf(o.w);
  *(ushort4*)(xb + (long)row * HD + tid * 4) = ob;
}

// ---------------- launch ----------------
extern "C" void kernel_launch(void* const* d_in, const int* in_sizes, int n_in,
                              void* d_out, int out_size, void* d_ws, size_t ws_size,
                              hipStream_t stream)
{
  const float* input = (const float*)d_in[0];
  const float* W[2]  = { (const float*)d_in[1], (const float*)d_in[8] };
  const float* R[2]  = { (const float*)d_in[2], (const float*)d_in[9] };
  const float* bb[2] = { (const float*)d_in[3], (const float*)d_in[10] };
  const float* pW[2] = { (const float*)d_in[4], (const float*)d_in[11] };
  const float* pb[2] = { (const float*)d_in[5], (const float*)d_in[12] };
  const float* gm[2] = { (const float*)d_in[6], (const float*)d_in[13] };
  const float* bt[2] = { (const float*)d_in[7], (const float*)d_in[14] };
  float* out = (float*)d_out;

  char* p = (char*)d_ws;
  size_t off = 0;
  auto alloc = [&](size_t bytes) { char* q = p + off; off += (bytes + 255) & ~(size_t)255; return (void*)q; };
  // tagged h exchange: 8 batches x 2 parity x 32 writer pages x 4KB = 2MB
  u64* hx = (u64*)alloc((size_t)NB * 2 * 32 * 4096);
  u16* xb     = (u16*)alloc((size_t)MROWS * HD * 2);
  u16* Wb[2]  = { (u16*)alloc((size_t)GD * HD * 2), (u16*)alloc((size_t)GD * HD * 2) };
  u16* Rbv[2] = { (u16*)alloc((size_t)GD * HD * 2), (u16*)alloc((size_t)GD * HD * 2) };
  u16* pWb[2] = { (u16*)alloc((size_t)HD * HD * 2), (u16*)alloc((size_t)HD * HD * 2) };
  u16* xpb    = (u16*)alloc((size_t)MROWS * GD * 2);
  u16* hs     = (u16*)alloc((size_t)MROWS * HD * 2);
  float* zb   = (float*)alloc((size_t)MROWS * HD * 4);
  float* x1   = (float*)alloc((size_t)MROWS * HD * 4);

  auto conv = [&](const float* src, u16* dst, long n) {
    int blocks = (int)((n / 4 + 255) / 256); if (blocks > 2048) blocks = 2048;
    k_tobf16<<<dim3(blocks), dim3(256), 0, stream>>>(src, dst, n);
  };
  conv(input, xb, (long)MROWS * HD);
  conv(W[0], Wb[0], (long)GD * HD);  conv(W[1], Wb[1], (long)GD * HD);
  conv(R[0], Rbv[0], (long)GD * HD); conv(R[1], Rbv[1], (long)GD * HD);
  conv(pW[0], pWb[0], (long)HD * HD); conv(pW[1], pWb[1], (long)HD * HD);

  // poison exchange buffer once per launch: 0xAAAA tag never targeted; cross-
  // replay tag aliasing is benign (deterministic replay -> identical values)
  hipMemsetAsync(hx, 0xAA, (size_t)NB * 2 * 32 * 4096, stream);

  for (int l = 0; l < 2; ++l) {
    // xp = x @ W.T + b  -> bf16, t-major layout
    k_gemm<0><<<dim3(GD / 128, MROWS / 128), 256, 0, stream>>>(
        xb, Wb[l], bb[l], nullptr, xpb, nullptr, GD, HD);
    // sLSTM scan: 256 WGs x 512 threads, 8 batch groups of 32
    k_scan<<<dim3(256), dim3(512), 0, stream>>>(xpb, Rbv[l], hs, hx, l * 1024);
    // z = gelu(hseq @ pW.T + pb) + x_res
    const float* resp = (l == 0) ? input : x1;
    k_gemm<1><<<dim3(HD / 128, MROWS / 128), 256, 0, stream>>>(
        hs, pWb[l], pb[l], resp, nullptr, zb, HD, HD);
    // layernorm -> fp32 x_next (+ bf16 copy for next layer's GEMM1)
    float* xo = (l == 0) ? x1 : out;
    k_ln<<<dim3(MROWS), dim3(256), 0, stream>>>(zb, gm[l], bt[l], xo, xb);
  }
}

// Round 13
// 4009.186 us; speedup vs baseline: 1.1939x; 1.1939x over previous
//
#include <hip/hip_runtime.h>
#include <cstdint>
#include <cmath>

typedef unsigned short u16;
typedef unsigned long long u64;
typedef __attribute__((ext_vector_type(8))) short short8;
typedef __attribute__((ext_vector_type(4))) float f32x4;

#define SEQ 1024
#define HD 1024
#define GD 4096
#define NB 8
#define MROWS 8192   // NB*SEQ

__device__ __forceinline__ u16 f2bf(float f) {
  union { float f; uint32_t u; } c; c.f = f;
  uint32_t u = c.u;
  uint32_t r = (u + 0x7fffu + ((u >> 16) & 1u)) >> 16;
  return (u16)r;
}
__device__ __forceinline__ float bf2f(u16 h) {
  union { uint32_t u; float f; } c; c.u = ((uint32_t)h) << 16;
  return c.f;
}

// ---------------- fp32 -> bf16 convert ----------------
__global__ void k_tobf16(const float* __restrict__ in, u16* __restrict__ out, long n) {
  long i = ((long)blockIdx.x * 256L + threadIdx.x) * 4;
  long st = (long)gridDim.x * 1024L;
  for (; i < n; i += st) {
    float4 v = *(const float4*)(in + i);
    ushort4 o;
    o.x = f2bf(v.x); o.y = f2bf(v.y); o.z = f2bf(v.z); o.w = f2bf(v.w);
    *(ushort4*)(out + i) = o;
  }
}

// ---------------- bf16 MFMA GEMM: C[m][n] = sum_k A[m][k]*Bw[n][k] (+epilogue) ----
// MODE 0: outb[(t*8+b)*4096 + col] = bf16(acc + bias[n])   (t-major for scan)
// MODE 1: outf = gelu(acc + bias[n]) + res[m][n]           (exact gelu)
template<int MODE>
__global__ __launch_bounds__(256, 1) void k_gemm(
    const u16* __restrict__ A, const u16* __restrict__ Bw,
    const float* __restrict__ bias, const float* __restrict__ res,
    u16* __restrict__ outb, float* __restrict__ outf, int N, int K)
{
  __shared__ u16 As[128][40];
  __shared__ u16 Bs[128][40];
  const int tid = threadIdx.x;
  const int wid = tid >> 6, lane = tid & 63;
  const int wm = wid >> 1, wn = wid & 1;
  const int r = lane & 15, q = lane >> 4;
  const long m0 = (long)blockIdx.y * 128, n0 = (long)blockIdx.x * 128;
  const int srow = tid >> 1, sseg = (tid & 1) * 16;

  f32x4 acc[4][4];
#pragma unroll
  for (int i = 0; i < 4; ++i)
#pragma unroll
    for (int j = 0; j < 4; ++j) acc[i][j] = (f32x4){0.f, 0.f, 0.f, 0.f};

  const u16* ag = A + (m0 + srow) * (long)K + sseg;
  const u16* bg = Bw + (n0 + srow) * (long)K + sseg;

  for (int k0 = 0; k0 < K; k0 += 32) {
    short8 av0 = *(const short8*)(ag + k0);
    short8 av1 = *(const short8*)(ag + k0 + 8);
    short8 bv0 = *(const short8*)(bg + k0);
    short8 bv1 = *(const short8*)(bg + k0 + 8);
    __syncthreads();
    *(short8*)&As[srow][sseg]     = av0;
    *(short8*)&As[srow][sseg + 8] = av1;
    *(short8*)&Bs[srow][sseg]     = bv0;
    *(short8*)&Bs[srow][sseg + 8] = bv1;
    __syncthreads();
    short8 bfr[4];
#pragma unroll
    for (int ni = 0; ni < 4; ++ni)
      bfr[ni] = *(const short8*)&Bs[wn * 64 + ni * 16 + r][q * 8];
#pragma unroll
    for (int mi = 0; mi < 4; ++mi) {
      short8 afr = *(const short8*)&As[wm * 64 + mi * 16 + r][q * 8];
#pragma unroll
      for (int ni = 0; ni < 4; ++ni)
        acc[mi][ni] = __builtin_amdgcn_mfma_f32_16x16x32_bf16(afr, bfr[ni], acc[mi][ni], 0, 0, 0);
    }
  }

#pragma unroll
  for (int mi = 0; mi < 4; ++mi)
#pragma unroll
    for (int ni = 0; ni < 4; ++ni) {
      long col = n0 + wn * 64 + ni * 16 + r;
      float bc = bias[col];
#pragma unroll
      for (int rr = 0; rr < 4; ++rr) {
        long row = m0 + wm * 64 + mi * 16 + q * 4 + rr;
        float v = acc[mi][ni][rr] + bc;
        if (MODE == 0) {
          long b = row >> 10, t = row & 1023;
          outb[((t * 8 + b) << 12) + col] = f2bf(v);
        } else {
          float ge = 0.5f * v * (1.0f + erff(v * 0.70710678118654752f));
          outf[row * N + col] = ge + res[row * N + col];
        }
      }
    }
}

// ---------------- persistent sLSTM scan: in-wave gates, no reduction --------
// 256 WGs x 512 threads (8 waves). b = wgid&7, c = wgid>>3. Wave w owns
// units [c*32 + w*4, +4) x all 4 gates = 16 rows x FULL k=1024 (weights as
// MFMA B-fragments, 32 x short8/lane, AGPR-resident). Per step:
//  1) all 512 lanes poll ONE tagged u64 of h_{i-1} (R11 protocol), untag->LDS
//  2) barrier (the only one)
//  3) per wave: 32 x {ds_read_b128 bcast A-frag + MFMA} -> complete pre for
//     its 16 rows in lanes 0-15; gates gathered by 3 shfls; state update in
//     lanes 0,4,8,12; publish 4 tagged words + hseq u64 from the SAME wave.
// No Dred, no gate wave, no hhist, no epilogue.
__global__ __launch_bounds__(512, 1) void k_scan(
    const u16* __restrict__ xp, const u16* __restrict__ Rb,
    u16* __restrict__ hseq, uint32_t* __restrict__ hx, int tagbase)
{
  __shared__ u16 hbuf[2][1024];       // staged h_{i-1} (bf16), parity ring

  const int tid = threadIdx.x;
  const int wgid = blockIdx.x;
  const int b = wgid & 7, c = wgid >> 3;
  const int lane = tid & 63;
  const int row = lane & 15, q = lane >> 4;
  const int u_loc = row >> 2, g = row & 3;
  const int unit0 = c * 32 + ((tid >> 6) << 2);     // wave's first unit

  // ---- weights: lane = B-fragment of R row (g*HD + unit0 + u_loc),
  //      k-slice m*32 + q*8 for m = 0..31 (full k = 1024)
  short8 wt[32];
  {
    const u16* src = Rb + ((long)(g * HD + unit0 + u_loc)) * HD + q * 8;
#pragma unroll
    for (int m = 0; m < 32; ++m)
      wt[m] = *(const short8*)(src + m * 32);
  }

  // xp prefetch registers; loader lanes 16..19 (q==1, row<4: gate s = row)
  const bool ldr = (q == 1 && row < 4);
  u64 xq_cur = 0, xq_nxt = 0;
  if (ldr) {
    xq_cur = *(const u64*)(xp + ((long)(0 * 8 + b) << 12) + row * 1024 + unit0);
    xq_nxt = *(const u64*)(xp + ((long)(1 * 8 + b) << 12) + row * 1024 + unit0);
  }

  float c_s = 0.f, n_s = 0.f, m_s = 0.f;
  const u64* hx64 = (const u64*)hx;

  for (int i = 0; i < SEQ; ++i) {
    // ---- stage h_{i-1}: each lane polls one self-validating tagged u64
    if (i > 0) {
      const unsigned tg = (unsigned)(tagbase + i - 1) & 0xffffu;
      const u64* src = hx64 + ((long)(b * 2 + ((i - 1) & 1)) << 9) + tid;
      u64 hv;
#pragma unroll 1
      for (;;) {
        hv = __hip_atomic_load(src, __ATOMIC_RELAXED, __HIP_MEMORY_SCOPE_AGENT);
        if ((((unsigned)(hv >> 16)) & 0xffffu) == tg &&
            ((unsigned)(hv >> 48)) == tg) break;
      }
      unsigned pk = ((unsigned)hv & 0xffffu) | (((unsigned)(hv >> 32)) << 16);
      *(uint32_t*)&hbuf[(i - 1) & 1][tid * 2] = pk;
    }
    __syncthreads();

    // ---- pre-activation: full-k MFMA; result lands in lanes 0-15 (D row 0)
    float pre = 0.f;
    if (i > 0) {
      const u16* hb = hbuf[(i - 1) & 1];
      f32x4 a0 = {0.f,0.f,0.f,0.f}, a1 = {0.f,0.f,0.f,0.f};
      f32x4 a2 = {0.f,0.f,0.f,0.f}, a3 = {0.f,0.f,0.f,0.f};
#pragma unroll
      for (int m = 0; m < 32; m += 4) {
        short8 v0 = *(const short8*)&hb[(m + 0) * 32 + q * 8];
        short8 v1 = *(const short8*)&hb[(m + 1) * 32 + q * 8];
        short8 v2 = *(const short8*)&hb[(m + 2) * 32 + q * 8];
        short8 v3 = *(const short8*)&hb[(m + 3) * 32 + q * 8];
        a0 = __builtin_amdgcn_mfma_f32_16x16x32_bf16(v0, wt[m + 0], a0, 0, 0, 0);
        a1 = __builtin_amdgcn_mfma_f32_16x16x32_bf16(v1, wt[m + 1], a1, 0, 0, 0);
        a2 = __builtin_amdgcn_mfma_f32_16x16x32_bf16(v2, wt[m + 2], a2, 0, 0, 0);
        a3 = __builtin_amdgcn_mfma_f32_16x16x32_bf16(v3, wt[m + 3], a3, 0, 0, 0);
      }
      pre = (a0[0] + a1[0]) + (a2[0] + a3[0]);
    }

    // ---- + xp (from loader lane 16+g, u16 slot u_loc)
    {
      u64 xv = __shfl(xq_cur, 16 + g, 64);
      pre += bf2f((u16)(xv >> (u_loc * 16)));
    }

    // ---- gates: gather i,f,z,o pres into lanes 0,4,8,12 (rows u*4)
    float p1 = __shfl_down(pre, 1, 64);
    float p2 = __shfl_down(pre, 2, 64);
    float p3 = __shfl_down(pre, 3, 64);
    float hval = 0.f;
    if (q == 0 && (row & 3) == 0) {
      float mn = fmaxf(p1 + m_s, pre);                // pre=i, p1=f, p2=z, p3=o
      float ig = __expf(pre - mn);
      float fg = __expf(p1 + m_s - mn);
      float e2 = __expf(2.f * p2);
      float th = 1.f - 2.f / (e2 + 1.f);              // tanh(z)
      c_s = fg * c_s + ig * th;
      n_s = fg * n_s + ig;
      m_s = mn;
      float og = 1.f / (1.f + __expf(-p3));
      hval = og * (c_s / n_s);
    }
    unsigned hu = (unsigned)f2bf(hval);
    unsigned h0 = __shfl(hu, 0, 64), h1 = __shfl(hu, 4, 64);
    unsigned h2 = __shfl(hu, 8, 64), h3 = __shfl(hu, 12, 64);

    // ---- publish (tagged, fire-and-forget) + hseq write, same wave
    if (lane < 2 && i < SEQ - 1) {
      const unsigned t16 = ((unsigned)(tagbase + i) & 0xffffu) << 16;
      u64 v64 = (lane == 0)
        ? ((u64)(t16 | h0) | ((u64)(t16 | h1) << 32))
        : ((u64)(t16 | h2) | ((u64)(t16 | h3) << 32));
      u64* dst = (u64*)hx + ((long)(b * 2 + (i & 1)) << 9) + (unit0 >> 1) + lane;
      __hip_atomic_store(dst, v64, __ATOMIC_RELAXED, __HIP_MEMORY_SCOPE_AGENT);
    }
    if (lane == 2) {
      u64 hp = (u64)(h0 | (h1 << 16)) | ((u64)(h2 | (h3 << 16)) << 32);
      *(u64*)(hseq + ((long)(b * SEQ + i)) * HD + unit0) = hp;
    }

    // ---- rotate xp prefetch (issued here, consumed next step's gate phase)
    xq_cur = xq_nxt;
    if (ldr && i + 2 < SEQ)
      xq_nxt = *(const u64*)(xp + ((long)((i + 2) * 8 + b) << 12) + row * 1024 + unit0);
  }
}

// ---------------- row LayerNorm (D=1024), fp32 out + bf16 copy ----------------
__global__ __launch_bounds__(256, 1) void k_ln(
    const float* __restrict__ z, const float* __restrict__ gamma, const float* __restrict__ beta,
    float* __restrict__ xout, u16* __restrict__ xb)
{
  const int row = blockIdx.x, tid = threadIdx.x;
  const float4 v = *(const float4*)(z + (long)row * HD + tid * 4);
  float s = v.x + v.y + v.z + v.w;
  float s2 = v.x * v.x + v.y * v.y + v.z * v.z + v.w * v.w;
#pragma unroll
  for (int off = 32; off > 0; off >>= 1) {
    s += __shfl_down(s, off, 64);
    s2 += __shfl_down(s2, off, 64);
  }
  __shared__ float red[8];
  const int wid = tid >> 6, lane = tid & 63;
  if (lane == 0) { red[wid] = s; red[4 + wid] = s2; }
  __syncthreads();
  float su = red[0] + red[1] + red[2] + red[3];
  float sq = red[4] + red[5] + red[6] + red[7];
  float mu = su * (1.f / 1024.f);
  float var = sq * (1.f / 1024.f) - mu * mu;
  float rs = rsqrtf(var + 1e-5f);
  const float4 g  = *(const float4*)(gamma + tid * 4);
  const float4 bt = *(const float4*)(beta + tid * 4);
  float4 o;
  o.x = (v.x - mu) * rs * g.x + bt.x;
  o.y = (v.y - mu) * rs * g.y + bt.y;
  o.z = (v.z - mu) * rs * g.z + bt.z;
  o.w = (v.w - mu) * rs * g.w + bt.w;
  *(float4*)(xout + (long)row * HD + tid * 4) = o;
  ushort4 ob;
  ob.x = f2bf(o.x); ob.y = f2bf(o.y); ob.z = f2bf(o.z); ob.w = f2bf(o.w);
  *(ushort4*)(xb + (long)row * HD + tid * 4) = ob;
}

// ---------------- launch ----------------
extern "C" void kernel_launch(void* const* d_in, const int* in_sizes, int n_in,
                              void* d_out, int out_size, void* d_ws, size_t ws_size,
                              hipStream_t stream)
{
  const float* input = (const float*)d_in[0];
  const float* W[2]  = { (const float*)d_in[1], (const float*)d_in[8] };
  const float* R[2]  = { (const float*)d_in[2], (const float*)d_in[9] };
  const float* bb[2] = { (const float*)d_in[3], (const float*)d_in[10] };
  const float* pW[2] = { (const float*)d_in[4], (const float*)d_in[11] };
  const float* pb[2] = { (const float*)d_in[5], (const float*)d_in[12] };
  const float* gm[2] = { (const float*)d_in[6], (const float*)d_in[13] };
  const float* bt[2] = { (const float*)d_in[7], (const float*)d_in[14] };
  float* out = (float*)d_out;

  char* p = (char*)d_ws;
  size_t off = 0;
  auto alloc = [&](size_t bytes) { char* q = p + off; off += (bytes + 255) & ~(size_t)255; return (void*)q; };
  uint32_t* hx = (uint32_t*)alloc(NB * 2 * HD * 4);   // 64KB tagged h exchange
  u16* xb     = (u16*)alloc((size_t)MROWS * HD * 2);
  u16* Wb[2]  = { (u16*)alloc((size_t)GD * HD * 2), (u16*)alloc((size_t)GD * HD * 2) };
  u16* Rbv[2] = { (u16*)alloc((size_t)GD * HD * 2), (u16*)alloc((size_t)GD * HD * 2) };
  u16* pWb[2] = { (u16*)alloc((size_t)HD * HD * 2), (u16*)alloc((size_t)HD * HD * 2) };
  u16* xpb    = (u16*)alloc((size_t)MROWS * GD * 2);
  u16* hs     = (u16*)alloc((size_t)MROWS * HD * 2);
  float* zb   = (float*)alloc((size_t)MROWS * HD * 4);
  float* x1   = (float*)alloc((size_t)MROWS * HD * 4);

  auto conv = [&](const float* src, u16* dst, long n) {
    int blocks = (int)((n / 4 + 255) / 256); if (blocks > 2048) blocks = 2048;
    k_tobf16<<<dim3(blocks), dim3(256), 0, stream>>>(src, dst, n);
  };
  conv(input, xb, (long)MROWS * HD);
  conv(W[0], Wb[0], (long)GD * HD);  conv(W[1], Wb[1], (long)GD * HD);
  conv(R[0], Rbv[0], (long)GD * HD); conv(R[1], Rbv[1], (long)GD * HD);
  conv(pW[0], pWb[0], (long)HD * HD); conv(pW[1], pWb[1], (long)HD * HD);

  // poison exchange buffer once per launch: 0xAAAA tag never targeted; cross-
  // replay tag aliasing is benign (deterministic replay -> identical values)
  hipMemsetAsync(hx, 0xAA, NB * 2 * HD * 4, stream);

  for (int l = 0; l < 2; ++l) {
    // xp = x @ W.T + b  -> bf16, t-major layout
    k_gemm<0><<<dim3(GD / 128, MROWS / 128), 256, 0, stream>>>(
        xb, Wb[l], bb[l], nullptr, xpb, nullptr, GD, HD);
    // sLSTM scan: 256 WGs x 512 threads, in-wave gates
    k_scan<<<dim3(256), dim3(512), 0, stream>>>(xpb, Rbv[l], hs, hx, l * 1024);
    // z = gelu(hseq @ pW.T + pb) + x_res
    const float* resp = (l == 0) ? input : x1;
    k_gemm<1><<<dim3(HD / 128, MROWS / 128), 256, 0, stream>>>(
        hs, pWb[l], pb[l], resp, nullptr, zb, HD, HD);
    // layernorm -> fp32 x_next (+ bf16 copy for next layer's GEMM1)
    float* xo = (l == 0) ? x1 : out;
    k_ln<<<dim3(MROWS), dim3(256), 0, stream>>>(zb, gm[l], bt[l], xo, xb);
  }
}